// Round 7
// baseline (1835.876 us; speedup 1.0000x reference)
//
#include <hip/hip_runtime.h>
#include <cstdint>
#include <cstddef>

#define TLEN 512
#define BATCH 1000
#define NEV 102400
#define HID 64
#define MAXCH 32
#define SBLK 400   // hist/scatter blocks per source = NEV/256
#define PB 128     // project blocks per (src, dir)

__device__ __forceinline__ float fast_rcp(float x) {
#if __has_builtin(__builtin_amdgcn_rcpf)
    return __builtin_amdgcn_rcpf(x);
#else
    return 1.0f / x;
#endif
}
__device__ __forceinline__ float sigm(float x) { return fast_rcp(1.0f + __expf(-x)); }
__device__ __forceinline__ float tanh_f(float x) { return fmaf(2.0f, sigm(2.0f * x), -1.0f); }

// wave-wide sum via DPP + readlane(63); ~6 VALU-latency ops.
template<int CTRL>
__device__ __forceinline__ float dpp_add(float x) {
    union { float f; int i; } u, v;
    u.f = x;
    v.i = __builtin_amdgcn_update_dpp(0, u.i, CTRL, 0xF, 0xF, true);
    return x + v.f;
}
__device__ __forceinline__ float wave_sum_all(float x) {
    x = dpp_add<0x111>(x);
    x = dpp_add<0x112>(x);
    x = dpp_add<0x114>(x);
    x = dpp_add<0x118>(x);
    x = dpp_add<0x142>(x);
    x = dpp_add<0x143>(x);
    union { float f; int i; } u; u.f = x;
    u.i = __builtin_amdgcn_readlane(u.i, 63);
    return u.f;
}

struct Src {
    const float* num;
    const int*   cat;
    const float* tab;
    const int*   bi;
    const int*   ti;
};

// ---------------------------------------------------------------------------
// compose: W'[row][col], rows: ccba 0-8, cdtx 9-26, cust 27-52, dp 53-119,
// remit 120-129 (last row of each = composed bias). col = dir*256 + gate row.
// ---------------------------------------------------------------------------
__global__ __launch_bounds__(512) void compose_kernel(
    const float* __restrict__ W0, const float* __restrict__ B0,
    const float* __restrict__ W1, const float* __restrict__ B1,
    const float* __restrict__ W2, const float* __restrict__ B2,
    const float* __restrict__ W3, const float* __restrict__ B3,
    const float* __restrict__ W4, const float* __restrict__ B4,
    const float* __restrict__ Wih, const float* __restrict__ bih,
    const float* __restrict__ bhh, float* __restrict__ wp)
{
    const int col = threadIdx.x;
    const int row = blockIdx.x;
    const float* srcW; const float* srcB; int base, IND;
    if (row < 9)        { srcW = W0; srcB = B0; base = 0;   IND = 8;  }
    else if (row < 27)  { srcW = W1; srcB = B1; base = 9;   IND = 17; }
    else if (row < 53)  { srcW = W2; srcB = B2; base = 27;  IND = 25; }
    else if (row < 120) { srcW = W3; srcB = B3; base = 53;  IND = 66; }
    else                { srcW = W4; srcB = B4; base = 120; IND = 9;  }
    const int j = row - base;
    const float* xrow = (j < IND) ? (srcW + (size_t)j * 64) : srcB;
    const float* wr = Wih + (size_t)col * 64;
    float acc = 0.0f;
#pragma unroll
    for (int h2 = 0; h2 < 64; ++h2) acc = fmaf(xrow[h2], wr[h2], acc);
    if (j == IND) acc += bih[col] + bhh[col];
    wp[(size_t)row * 512 + col] = acc;
}

// ---------------------------------------------------------------------------
// Counting sort of events into (src, time-segment) buckets.
// ---------------------------------------------------------------------------
__device__ __forceinline__ const int* pick_ti(int src, Src s0, Src s1, Src s2, Src s3, Src s4) {
    return (src == 0) ? s0.ti : (src == 1) ? s1.ti :
           (src == 2) ? s2.ti : (src == 3) ? s3.ti : s4.ti;
}

__global__ __launch_bounds__(256) void hist_kernel(
    Src s0, Src s1, Src s2, Src s3, Src s4,
    int lgseg, int S, int* __restrict__ blockhist)
{
    __shared__ int bins[MAXCH];
    const int g = blockIdx.x;
    const int src = g / SBLK, blk = g - src * SBLK;
    const int* ti = pick_ti(src, s0, s1, s2, s3, s4);
    if (threadIdx.x < S) bins[threadIdx.x] = 0;
    __syncthreads();
    const int e = blk * 256 + threadIdx.x;       // NEV == SBLK*256 exactly
    const int c = ti[e] >> lgseg;
    atomicAdd(&bins[c], 1);
    __syncthreads();
    if (threadIdx.x < S)
        blockhist[(size_t)(src * S + threadIdx.x) * SBLK + blk] = bins[threadIdx.x];
}

__global__ __launch_bounds__(512) void scan_kernel(
    int* __restrict__ blockhist, int* __restrict__ cnt)
{
    __shared__ int arr[512];
    const int s = blockIdx.x;
    const int i = threadIdx.x;
    const int v = (i < SBLK) ? blockhist[(size_t)s * SBLK + i] : 0;
    arr[i] = v;
    __syncthreads();
#pragma unroll
    for (int d = 1; d < 512; d <<= 1) {
        int t = (i >= d) ? arr[i - d] : 0;
        __syncthreads();
        arr[i] += t;
        __syncthreads();
    }
    if (i < SBLK) blockhist[(size_t)s * SBLK + i] = arr[i] - v;
    if (i == 511) cnt[s] = arr[511];
}

__global__ __launch_bounds__(256) void scatter_kernel(
    Src s0, Src s1, Src s2, Src s3, Src s4,
    int lgseg, int S, int cap,
    const int* __restrict__ blockhist, int* __restrict__ evlist)
{
    __shared__ int off[MAXCH];
    const int g = blockIdx.x;
    const int src = g / SBLK, blk = g - src * SBLK;
    const int* ti = pick_ti(src, s0, s1, s2, s3, s4);
    if (threadIdx.x < S)
        off[threadIdx.x] = blockhist[(size_t)(src * S + threadIdx.x) * SBLK + blk];
    __syncthreads();
    const int e = blk * 256 + threadIdx.x;
    const int c = ti[e] >> lgseg;
    const int slot = atomicAdd(&off[c], 1);
    if (slot < cap) evlist[(size_t)(src * S + c) * cap + slot] = e;
}

// ---------------------------------------------------------------------------
// project one direction's gates for one time segment into buf[1000][seg][256]:
// buf[(bi*seg + ti-t0)*256 + col] = b'[dcol+col] + sum_j x[j]*W'[j][dcol+col]
// ---------------------------------------------------------------------------
template<int NNUM, int NCAT>
__device__ __forceinline__ void project_seg(
    const Src s, const float* __restrict__ wp, const int dcol,
    float* __restrict__ buf, const int* __restrict__ list, const int n,
    const int t0, const int seg, const int i0, const int stride)
{
    constexpr int IND = NCAT * 8 + NNUM;
    constexpr int NC = NCAT > 0 ? NCAT : 1;
    const int col = threadIdx.x;
    float wcol[IND];
#pragma unroll
    for (int j = 0; j < IND; ++j) wcol[j] = wp[(size_t)j * 512 + dcol + col];
    const float bcol = wp[(size_t)IND * 512 + dcol + col];

    int i = i0;
    if (i >= n) return;

    int ev = list[i];
    int nbi = s.bi[ev], nti = s.ti[ev];
    int ncat[NC]; float nnum[NNUM ? NNUM : 1];
#pragma unroll
    for (int c = 0; c < NCAT; ++c) ncat[c] = s.cat[ev * NCAT + c];
#pragma unroll
    for (int u = 0; u < NNUM; ++u) nnum[u] = s.num[(size_t)ev * NNUM + u];

    while (true) {
        const int cbi = nbi, cti = nti;
        int ccat[NC]; float cnum[NNUM ? NNUM : 1];
#pragma unroll
        for (int c = 0; c < NCAT; ++c) ccat[c] = ncat[c];
#pragma unroll
        for (int u = 0; u < NNUM; ++u) cnum[u] = nnum[u];

        const int ni = i + stride;
        if (ni < n) {
            ev = list[ni];
            nbi = s.bi[ev]; nti = s.ti[ev];
#pragma unroll
            for (int c = 0; c < NCAT; ++c) ncat[c] = s.cat[ev * NCAT + c];
#pragma unroll
            for (int u = 0; u < NNUM; ++u) nnum[u] = s.num[(size_t)ev * NNUM + u];
        }

        float acc = bcol;
#pragma unroll
        for (int c = 0; c < NCAT; ++c) {
            const float* tr = s.tab + (size_t)ccat[c] * 8;
#pragma unroll
            for (int u = 0; u < 8; ++u)
                acc = fmaf(tr[u], wcol[c * 8 + u], acc);
        }
#pragma unroll
        for (int u = 0; u < NNUM; ++u)
            acc = fmaf(cnum[u], wcol[NCAT * 8 + u], acc);

        buf[((size_t)cbi * seg + (cti - t0)) * 256 + col] = acc;

        i = ni;
        if (i >= n) break;
    }
}

// ---------------------------------------------------------------------------
// recurrence over one time segment for one (b, dir) wave; state carried in ws.
// ---------------------------------------------------------------------------
__device__ __forceinline__ void rec_seg_wave(
    const float* __restrict__ buf, const float* __restrict__ Whh,
    const float* __restrict__ Whr, float* __restrict__ h0,
    float* __restrict__ hstate, float* __restrict__ cstate,
    int t0, int seg, int bl, int dir, bool first)
{
    const int lane = threadIdx.x & 63;

    float whh4[4];
#pragma unroll
    for (int k = 0; k < 4; ++k) whh4[k] = Whh[dir * 256 + k * 64 + lane];
    const float whr = Whr[dir * HID + lane];

    float h, c;
    if (first) { h = 0.0f; c = 0.0f; }
    else {
        h = hstate[dir * BATCH + bl];
        c = cstate[(size_t)(dir * BATCH + bl) * 64 + lane];
    }

    const float* gb = buf + (size_t)bl * seg * 256 + lane;
    float* h0p = h0 + (size_t)bl * TLEN * 2 + dir;

    auto addr = [&](int stp) -> const float* {
        int sc = stp < seg ? stp : seg - 1;     // clamp (value unused past end)
        int dt = dir ? (seg - 1 - sc) : sc;
        return gb + (size_t)dt * 256;
    };

    float P[8][4];
#pragma unroll
    for (int d = 0; d < 8; ++d) {
        const float* pa = addr(d);
#pragma unroll
        for (int k = 0; k < 4; ++k) P[d][k] = pa[k * 64];
    }

    for (int st = 0; st < seg; st += 8) {
        float N[8][4];
#pragma unroll
        for (int d = 0; d < 8; ++d) {
            const float* pn = addr(st + 8 + d);
#pragma unroll
            for (int k = 0; k < 4; ++k) N[d][k] = pn[k * 64];
        }
#pragma unroll
        for (int d = 0; d < 8; ++d) {
            float gi = fmaf(whh4[0], h, P[d][0]);
            float gf = fmaf(whh4[1], h, P[d][1]);
            float gg = fmaf(whh4[2], h, P[d][2]);
            float go = fmaf(whh4[3], h, P[d][3]);
            c = sigm(gf) * c + sigm(gi) * tanh_f(gg);
            float pp = sigm(go) * tanh_f(c) * whr;
            h = wave_sum_all(pp);
            const int dt = dir ? (seg - 1 - (st + d)) : (st + d);
            if (lane == 0) h0p[(size_t)(t0 + dt) * 2] = h;
        }
#pragma unroll
        for (int d = 0; d < 8; ++d)
#pragma unroll
            for (int k = 0; k < 4; ++k) P[d][k] = N[d][k];
    }

    if (lane == 0) hstate[dir * BATCH + bl] = h;
    cstate[(size_t)(dir * BATCH + bl) * 64 + lane] = c;
}

// ---------------------------------------------------------------------------
// fused pipeline stage over TIME segments:
//   blocks [0, RB):            rec_fwd(seg k-1) / rec_bwd(seg S-k) interleaved
//   blocks [RB, RB+640):       proj_fwd(seg k)   (5 src x PB blocks)
//   blocks [RB+640, RB+1280):  proj_bwd(seg S-1-k)
// ---------------------------------------------------------------------------
__global__ __launch_bounds__(256) void fused_stage(
    Src s0, Src s1, Src s2, Src s3, Src s4,
    const float* __restrict__ wp,
    float* __restrict__ pfbuf, float* __restrict__ pbbuf,
    const float* __restrict__ rfbuf, const float* __restrict__ rbbuf,
    const int* __restrict__ cnt, const int* __restrict__ evlist,
    int cap, int S, int seg, int k, int RB,
    const float* __restrict__ Whh, const float* __restrict__ Whr,
    float* __restrict__ h0, float* __restrict__ hstate, float* __restrict__ cstate)
{
    if ((int)blockIdx.x < RB) {
        // 500 rec blocks: even -> fwd, odd -> bwd; 4 waves x 1 pair each
        const int dir = blockIdx.x & 1;
        const int bl = (blockIdx.x >> 1) * 4 + (threadIdx.x >> 6);
        const int t0 = dir ? (S - k) * seg : (k - 1) * seg;
        const float* buf = dir ? rbbuf : rfbuf;
        rec_seg_wave(buf, Whh, Whr, h0, hstate, cstate, t0, seg, bl, dir, k == 1);
        return;
    }
    const int g = blockIdx.x - RB;
    const int dir = (g >= 5 * PB) ? 1 : 0;
    const int gg = g - dir * 5 * PB;
    const int src = gg / PB;
    const int i0 = gg - src * PB;
    const int tseg = dir ? (S - 1 - k) : k;
    const int t0 = tseg * seg;
    float* buf = dir ? pbbuf : pfbuf;
    const int dcol = dir * 256;
    int n = cnt[src * S + tseg];
    if (n > cap) n = cap;
    const int* list = evlist + (size_t)(src * S + tseg) * cap;
    switch (src) {
        case 0: project_seg<8, 0>(s0, wp,              dcol, buf, list, n, t0, seg, i0, PB); break;
        case 1: project_seg<1, 2>(s1, wp + 9 * 512,    dcol, buf, list, n, t0, seg, i0, PB); break;
        case 2: project_seg<1, 3>(s2, wp + 27 * 512,   dcol, buf, list, n, t0, seg, i0, PB); break;
        case 3: project_seg<2, 8>(s3, wp + 53 * 512,   dcol, buf, list, n, t0, seg, i0, PB); break;
        default: project_seg<1, 1>(s4, wp + 120 * 512, dcol, buf, list, n, t0, seg, i0, PB); break;
    }
}

// ---------------------------------------------------------------------------
// LSTM layer 1 (insz=2), one wave per (b,dir), 8-step x prefetch, DPP reduce.
// ---------------------------------------------------------------------------
__global__ __launch_bounds__(256) void lstm1_kernel(
    const float* __restrict__ h0, const float* __restrict__ Wih,
    const float* __restrict__ Whh, const float* __restrict__ Whr,
    const float* __restrict__ bih, const float* __restrict__ bhh,
    float* __restrict__ h1)
{
    int w = threadIdx.x >> 6, lane = threadIdx.x & 63;
    int p = blockIdx.x * 4 + w;
    int b = p >> 1, dir = p & 1;

    float wi0[4], wi1[4], whh[4], bias[4];
#pragma unroll
    for (int k = 0; k < 4; ++k) {
        int r = k * 64 + lane;
        wi0[k] = Wih[(size_t)(dir * 256 + r) * 2 + 0];
        wi1[k] = Wih[(size_t)(dir * 256 + r) * 2 + 1];
        whh[k] = Whh[dir * 256 + r];
        bias[k] = bih[dir * 256 + r] + bhh[dir * 256 + r];
    }
    float whr = Whr[dir * HID + lane];
    float h = 0.0f, c = 0.0f;
    const float* hb = h0 + (size_t)b * TLEN * 2;

    auto xat = [&](int t) -> float2 {
        int tc = t < TLEN ? t : TLEN - 1;
        int tt = dir ? (TLEN - 1 - tc) : tc;
        return *(const float2*)(hb + (size_t)tt * 2);
    };

    float2 X[8];
#pragma unroll
    for (int d = 0; d < 8; ++d) X[d] = xat(d);

    for (int t = 0; t < TLEN; t += 8) {
        float2 N[8];
#pragma unroll
        for (int d = 0; d < 8; ++d) N[d] = xat(t + 8 + d);
#pragma unroll
        for (int d = 0; d < 8; ++d) {
            float g[4];
#pragma unroll
            for (int k = 0; k < 4; ++k)
                g[k] = fmaf(whh[k], h, fmaf(wi1[k], X[d].y, fmaf(wi0[k], X[d].x, bias[k])));
            c = sigm(g[1]) * c + sigm(g[0]) * tanh_f(g[2]);
            float pp = sigm(g[3]) * tanh_f(c) * whr;
            h = wave_sum_all(pp);
            int tt = dir ? (TLEN - 1 - (t + d)) : (t + d);
            if (lane == 0) h1[((size_t)b * TLEN + tt) * 2 + dir] = h;
        }
#pragma unroll
        for (int d = 0; d < 8; ++d) X[d] = N[d];
    }
}

__global__ __launch_bounds__(256) void mean_kernel(
    const float2* __restrict__ h1, float* __restrict__ out)
{
    int i = blockIdx.x * 256 + threadIdx.x;
    if (i < BATCH * TLEN) {
        float2 v = h1[i];
        out[i] = 0.5f * (v.x + v.y);
    }
}

// ===========================================================================
extern "C" void kernel_launch(void* const* d_in, const int* in_sizes, int n_in,
                              void* d_out, int out_size, void* d_ws, size_t ws_size,
                              hipStream_t stream)
{
    Src s0 = { (const float*)d_in[0], nullptr, nullptr,
               (const int*)d_in[1], (const int*)d_in[2] };
    const float* ccba_W = (const float*)d_in[3];
    const float* ccba_b = (const float*)d_in[4];
    Src s1 = { (const float*)d_in[5], (const int*)d_in[6], (const float*)d_in[7],
               (const int*)d_in[8], (const int*)d_in[9] };
    const float* cdtx_W = (const float*)d_in[10];
    const float* cdtx_b = (const float*)d_in[11];
    Src s2 = { (const float*)d_in[12], (const int*)d_in[13], (const float*)d_in[14],
               (const int*)d_in[15], (const int*)d_in[16] };
    const float* cust_W = (const float*)d_in[17];
    const float* cust_b = (const float*)d_in[18];
    Src s3 = { (const float*)d_in[19], (const int*)d_in[20], (const float*)d_in[21],
               (const int*)d_in[22], (const int*)d_in[23] };
    const float* dp_W = (const float*)d_in[24];
    const float* dp_b = (const float*)d_in[25];
    Src s4 = { (const float*)d_in[26], (const int*)d_in[27], (const float*)d_in[28],
               (const int*)d_in[29], (const int*)d_in[30] };
    const float* remit_W = (const float*)d_in[31];
    const float* remit_b = (const float*)d_in[32];
    const float* Wih0 = (const float*)d_in[33];
    const float* Whh0 = (const float*)d_in[34];
    const float* Whr0 = (const float*)d_in[35];
    const float* bih0 = (const float*)d_in[36];
    const float* bhh0 = (const float*)d_in[37];
    const float* Wih1 = (const float*)d_in[38];
    const float* Whh1 = (const float*)d_in[39];
    const float* Whr1 = (const float*)d_in[40];
    const float* bih1 = (const float*)d_in[41];
    const float* bhh1 = (const float*)d_in[42];
    float* out = (float*)d_out;

    // ---- pick largest time-segment that fits: 4 buffers of 1000*seg*256*4 ----
    int seg = 16;
    {
        const int cand[4] = {128, 64, 32, 16};
        for (int ci = 0; ci < 4; ++ci) {
            int sg = cand[ci];
            int Sc = TLEN / sg;
            int cp = BATCH * sg; if (cp > NEV) cp = NEV;
            size_t bufs = 4 * (size_t)BATCH * sg * 256 * 4;
            size_t lists = (size_t)5 * Sc * cp * 4;
            size_t bh = (size_t)5 * Sc * SBLK * 4;
            size_t need = bufs + lists + bh + 1024 + 8192 + 512000
                        + (size_t)4096000 * 2 + 266240 + 4096;
            if (need <= ws_size) { seg = sg; break; }
        }
    }
    const int S = TLEN / seg;
    int lgseg = 0; while ((1 << lgseg) < seg) ++lgseg;
    int cap = BATCH * seg; if (cap > NEV) cap = NEV;

    const size_t bufb = (size_t)BATCH * seg * 256 * 4;
    char* p = (char*)d_ws;
    float* bufF[2] = { (float*)p, (float*)(p + bufb) };
    float* bufB[2] = { (float*)(p + 2 * bufb), (float*)(p + 3 * bufb) };
    size_t off = 4 * bufb;
    int*   evlist    = (int*)(p + off);   off += ((size_t)5 * S * cap * 4 + 255) & ~(size_t)255;
    int*   blockhist = (int*)(p + off);   off += ((size_t)5 * S * SBLK * 4 + 255) & ~(size_t)255;
    int*   cnt       = (int*)(p + off);   off += 1024;
    float* hstate    = (float*)(p + off); off += 8192;
    float* cstate    = (float*)(p + off); off += 512000;
    float* h0        = (float*)(p + off); off += 4096000;
    float* h1        = (float*)(p + off); off += 4096000;
    float* wp        = (float*)(p + off);

    // ---- one-time per call ----
    compose_kernel<<<130, 512, 0, stream>>>(
        ccba_W, ccba_b, cdtx_W, cdtx_b, cust_W, cust_b,
        dp_W, dp_b, remit_W, remit_b, Wih0, bih0, bhh0, wp);

    hist_kernel<<<5 * SBLK, 256, 0, stream>>>(s0, s1, s2, s3, s4, lgseg, S, blockhist);
    scan_kernel<<<5 * S, 512, 0, stream>>>(blockhist, cnt);
    scatter_kernel<<<5 * SBLK, 256, 0, stream>>>(s0, s1, s2, s3, s4, lgseg, S, cap,
                                                 blockhist, evlist);

    // ---- time-pipelined stages ----
    for (int k = 0; k <= S; ++k) {
        const int RB = (k >= 1) ? 500 : 0;          // 500 blocks = 2000 rec waves
        const int PJ = (k < S) ? 10 * PB : 0;       // 2 dirs x 5 src x PB blocks
        const int grid = RB + PJ;
        fused_stage<<<grid, 256, 0, stream>>>(
            s0, s1, s2, s3, s4, wp,
            bufF[k & 1], bufB[k & 1],
            bufF[(k - 1) & 1], bufB[(k - 1) & 1],
            cnt, evlist, cap, S, seg, k, RB,
            Whh0, Whr0, h0, hstate, cstate);
    }

    lstm1_kernel<<<(BATCH * 2) / 4, 256, 0, stream>>>(
        h0, Wih1, Whh1, Whr1, bih1, bhh1, h1);
    mean_kernel<<<(BATCH * TLEN + 255) / 256, 256, 0, stream>>>(
        (const float2*)h1, out);
}